// Round 2
// baseline (74.363 us; speedup 1.0000x reference)
//
#include <hip/hip_runtime.h>

// Problem constants
#define BB 8
#define CIN 16
#define COUT 64
#define HH 32
#define WW 32

// denom = 2*N_EKV*VT = 0.075. Everything in log2-units:
//   b1 = (x - clip(theta,1,8)) * C,  C = log2(e)/0.075;  b2 = b1 - 0.1*C
// Reference clip(a,-50,20) == post-log l = min(log2(1+2^b), B_HI) (fp32-exact).
// d <= -0.72 (b1 <= -13.85): f < 5e-9 -> skip via wave-uniform branch.
#define SCALE_C 19.235933878519388f /* (1/0.075)*log2(e) */
#define K2V (SCALE_C * 0.1f)        /* b2 = b1 - K2V */
#define B_HI 28.85390081777927f     /* 20*log2e */
#define WINLO_S (-13.849872392533959f) /* -0.72 * SCALE_C */
// final scale: ln2^2 * ALPHA * R (times runtime `scale`)
#define OUT_CONST (0.4804530139182014f * 0.05625f * 0.1f)
// OOB-lane sentinel: far below WINLO_S; LUT clamp maps it to T[0] ~ 4e-9,
// matching the reference's zero-pad contribution (~1e-12) within 1e-6 total.
#define VNEG (-1.0e4f)

#define EXP2F(x) __builtin_amdgcn_exp2f(x)
#define LOG2F(x) __builtin_amdgcn_logf(x)

// f-LUT: per-tap nonlinearity is single-variable in b1:
//   f(b1) = min(log2(1+2^b1),B_HI)^2 - min(log2(1+2^(b1-K2V)),B_HI)^2
// tabulated at b1 = (i - 234)*TAB_H, i = 0..746, TAB_H = SCALE_C/320.
// Both slope-kinks (u=714, u=746) land exactly on knots -> zero kink error;
// curved region lerp err <= ~2e-3 in f-units (~1e-5 in output units).
// Clamped lanes (b1 << 0) read T[0] -> same-address LDS broadcast.
#define TAB_H (SCALE_C / 320.0f)
#define TAB_INVH (320.0f / SCALE_C)
#define TAB_OFF 234.0f
#define TAB_UMAX 746.5f
#define TAB_LAST 746
#define TAB_N 752 /* 746 real + zero pad for the i+1 read */

// Fused single-kernel version: no init_kernel, no workspace.
// Per block: build f-LUT (752 trans evals) + clip/scale this block's 144
// theta values into LDS; main loop reads x DIRECTLY with clamped addresses
// + per-tap validity masks (replaces the padded-xp staging round-trip).
//
// Block mapping (MI355X round-robin dispatch: bid%8 -> XCD, then sequential
// fill): the 8 co-resident blocks on a CU share the SAME (b,tile) 20KB
// x-slice (L1-resident) and differ only in co:
//   b = bid&7, tile = (bid>>3)&3, co = (bid>>8)*8 + ((bid>>5)&7)
__device__ __forceinline__ void load9g(const float* __restrict__ p, const int* off9,
                                       float* v) {
#pragma unroll
    for (int k = 0; k < 9; ++k) v[k] = p[off9[k]];
}

__device__ __forceinline__ void compute9(const float* v, const float* __restrict__ TH,
                                         int cin, const bool* val9,
                                         const float* __restrict__ T, float* acc) {
    float th9[9];
#pragma unroll
    for (int k = 0; k < 9; ++k) th9[k] = TH[cin * 9 + k]; // uniform ds_read: broadcast
#pragma unroll
    for (int k = 0; k < 9; ++k) {
        float b1 = fmaf(v[k], SCALE_C, -th9[k]);
        b1 = val9[k] ? b1 : VNEG; // one cndmask; mask precomputed (SGPR pair)
        if (__any(b1 > WINLO_S)) {
            float u = fmaf(b1, TAB_INVH, TAB_OFF);
            u = fminf(fmaxf(u, 0.0f), TAB_UMAX); // v_med3
            float fi = floorf(u);
            float fr = u - fi;
            int i = (int)fi;
            float t0 = T[i];
            float t1 = T[i + 1]; // ds_read2_b32 with t0
            float a = acc[k % 3];
            a += fmaf(fr, t1 - t0, t0);
            acc[k % 3] = a;
        }
    }
}

__global__ __launch_bounds__(256, 8) void ekv_fused(const float* __restrict__ x,
                                                    const float* __restrict__ theta,
                                                    const float* __restrict__ scale,
                                                    float* __restrict__ out) {
    __shared__ float T[TAB_N];
    __shared__ float TH[CIN * 9];

    int bid = blockIdx.x;
    int b = bid & 7;
    int tile = (bid >> 3) & 3;
    int cl = (bid >> 5) & 7;
    int cm = bid >> 8;
    int co = cm * 8 + cl;

    int t = threadIdx.x;

    // Build the f-table once per block (transcendentals live only here).
    for (int i = t; i < TAB_N; i += 256) {
        float val = 0.0f;
        if (i <= TAB_LAST) {
            float b1 = ((float)i - TAB_OFF) * TAB_H;
            float e1 = EXP2F(b1);
            float l1 = fminf(LOG2F(1.0f + e1), B_HI);
            float e2 = EXP2F(b1 - K2V);
            float l2 = fminf(LOG2F(1.0f + e2), B_HI);
            val = fmaf(l1, l1, -(l2 * l2));
        }
        T[i] = val;
    }
    // Clip+scale this block's theta row (144 floats, one coalesced read).
    if (t < CIN * 9) {
        TH[t] = fminf(fmaxf(theta[co * (CIN * 9) + t], 1.0f), 8.0f) * SCALE_C;
    }
    __syncthreads();

    int ow = t & 31;
    int oh = tile * 8 + (t >> 5);

    // Per-tap clamped offsets + validity (computed once, reused for all cin).
    int yoff[3], col[3];
    bool vy[3], vx[3];
#pragma unroll
    for (int d = 0; d < 3; ++d) {
        int y = oh - 1 + d;
        vy[d] = ((unsigned)y < HH);
        yoff[d] = (y < 0 ? 0 : (y > HH - 1 ? HH - 1 : y)) * WW;
        int c = ow - 1 + d;
        vx[d] = ((unsigned)c < WW);
        col[d] = (c < 0 ? 0 : (c > WW - 1 ? WW - 1 : c));
    }
    int off9[9];
    bool val9[9];
#pragma unroll
    for (int dy = 0; dy < 3; ++dy)
#pragma unroll
        for (int dx = 0; dx < 3; ++dx) {
            off9[dy * 3 + dx] = yoff[dy] + col[dx];
            val9[dy * 3 + dx] = vy[dy] && vx[dx];
        }

    const float* xb = x + (size_t)b * (CIN * HH * WW);

    float acc[3] = {0.0f, 0.0f, 0.0f};

    // Register ping-pong over cin: prefetch next plane's 9 taps while current
    // plane's 9 evals run.
    float va[9], vb[9];
    load9g(xb, off9, va);
#pragma unroll 1
    for (int cin = 0; cin < CIN; cin += 2) {
        load9g(xb + (cin + 1) * (HH * WW), off9, vb);
        compute9(va, TH, cin, val9, T, acc);
        int nc = cin + 2 < CIN ? cin + 2 : CIN - 1; // clamp: harmless re-read
        load9g(xb + nc * (HH * WW), off9, va);
        compute9(vb, TH, cin + 1, val9, T, acc);
    }

    float sc = scale[0] * (OUT_CONST);
    out[(((size_t)b * COUT + co) * HH + oh) * WW + ow] =
        (acc[0] + acc[1] + acc[2]) * sc;
}

extern "C" void kernel_launch(void* const* d_in, const int* in_sizes, int n_in,
                              void* d_out, int out_size, void* d_ws, size_t ws_size,
                              hipStream_t stream) {
    const float* x = (const float*)d_in[0];
    const float* theta = (const float*)d_in[1];
    const float* scale = (const float*)d_in[2];
    float* out = (float*)d_out;
    (void)d_ws;
    (void)ws_size;

    ekv_fused<<<BB * 4 * COUT, 256, 0, stream>>>(x, theta, scale, out);
}